// Round 23
// baseline (813.552 us; speedup 1.0000x reference)
//
#include <hip/hip_runtime.h>

#define B_ 64
#define T_ 512
#define F_ 1024
#define U_ 64

// lgkm-only barrier: orders LDS ops across the block WITHOUT draining vmcnt,
// so the producer's pipelined global loads stay in flight across steps.
// Safe here because the consumer loop has ZERO VMEM ops (pot is in LDS) --
// the R5/R11 lgkm-barrier penalty (post-barrier vmcnt serialization) cannot
// apply to it.
__device__ __forceinline__ void bar_lds() {
    asm volatile("s_waitcnt lgkmcnt(0)" ::: "memory");
    __builtin_amdgcn_s_barrier();
    asm volatile("" ::: "memory");
}

// ---------------------------------------------------------------------------
// FUSED kernel v2: one block (8 waves, 512 thr) per batch.
//   waves 0-3: VERBATIM R6 viterbi step (best measured form), pot from LDS.
//   waves 4-7: producer GEMM, one 16-k slice per step, with a DISTANCE-1
//     x-register pipeline (xvA/xvB ping-pong, issued one step ahead) and
//     w loads issued BEFORE the x-next loads (compiler waits vmcnt(16) for
//     w, leaving x-next in flight). R22 failed because loads were consumed
//     in-step (~900cy stall/step); this version hides that latency under
//     the consumer-paced step.
//   Chunk c (64 rows) written at step (c-1)*64+63 region2; consumer first
//   reads it at step c*64 region1; same-buffer last read 64 steps before
//   the write. GEMM arithmetic: ascending k, sequential fmaf per output --
//   bit-identical to the validated standalone GEMM (R22 absmax=0).
// LDS ~67KB.
// ---------------------------------------------------------------------------
__global__ __launch_bounds__(512) void crf_fused_kernel(
    const float* __restrict__ x, const float* __restrict__ w,
    const float* __restrict__ bias, const float* __restrict__ chain,
    const float* __restrict__ lb, const float* __restrict__ rb,
    int* __restrict__ path)
{
    const int b = blockIdx.x;
    const int tid = threadIdx.x;
    const int lane = tid & 63;
    const int wave = tid >> 6;            // 0..7
    const bool cons = (wave < 4);
    const int g = wave & 3;               // consumer wave role
    const int u = lane;

    __shared__ __align__(16) float potl[2][64][64];   // 32 KB pot chunks
    __shared__ __align__(16) float alpha_s[64];
    __shared__ float pval[4][64];
    __shared__ int   pidx[4][64];
    __shared__ unsigned char bp[T_ - 1][64];          // 32704 B
    __shared__ unsigned char cmap[4][64];
    __shared__ int es[4];

    // ---------- prologue: chunk 0 (rows 0..63) by ALL 512 threads ----------
    {
        const int rt = tid >> 4;          // 32 groups x 2 rows
        const int u0 = (tid & 15) * 4;
        float a0[4] = {0.f, 0.f, 0.f, 0.f};
        float a1[4] = {0.f, 0.f, 0.f, 0.f};
        const float* xr = x + ((size_t)b * T_ + rt * 2) * F_;
        for (int k4 = 0; k4 < F_ / 4; ++k4) {
            const float4 x0 = *reinterpret_cast<const float4*>(xr + k4 * 4);
            const float4 x1 = *reinterpret_cast<const float4*>(xr + F_ + k4 * 4);
            const float4 w0 = *reinterpret_cast<const float4*>(w + (size_t)(k4 * 4 + 0) * U_ + u0);
            const float4 w1 = *reinterpret_cast<const float4*>(w + (size_t)(k4 * 4 + 1) * U_ + u0);
            const float4 w2 = *reinterpret_cast<const float4*>(w + (size_t)(k4 * 4 + 2) * U_ + u0);
            const float4 w3 = *reinterpret_cast<const float4*>(w + (size_t)(k4 * 4 + 3) * U_ + u0);
            a0[0] = fmaf(x0.x, w0.x, a0[0]); a0[1] = fmaf(x0.x, w0.y, a0[1]);
            a0[2] = fmaf(x0.x, w0.z, a0[2]); a0[3] = fmaf(x0.x, w0.w, a0[3]);
            a1[0] = fmaf(x1.x, w0.x, a1[0]); a1[1] = fmaf(x1.x, w0.y, a1[1]);
            a1[2] = fmaf(x1.x, w0.z, a1[2]); a1[3] = fmaf(x1.x, w0.w, a1[3]);
            a0[0] = fmaf(x0.y, w1.x, a0[0]); a0[1] = fmaf(x0.y, w1.y, a0[1]);
            a0[2] = fmaf(x0.y, w1.z, a0[2]); a0[3] = fmaf(x0.y, w1.w, a0[3]);
            a1[0] = fmaf(x1.y, w1.x, a1[0]); a1[1] = fmaf(x1.y, w1.y, a1[1]);
            a1[2] = fmaf(x1.y, w1.z, a1[2]); a1[3] = fmaf(x1.y, w1.w, a1[3]);
            a0[0] = fmaf(x0.z, w2.x, a0[0]); a0[1] = fmaf(x0.z, w2.y, a0[1]);
            a0[2] = fmaf(x0.z, w2.z, a0[2]); a0[3] = fmaf(x0.z, w2.w, a0[3]);
            a1[0] = fmaf(x1.z, w2.x, a1[0]); a1[1] = fmaf(x1.z, w2.y, a1[1]);
            a1[2] = fmaf(x1.z, w2.z, a1[2]); a1[3] = fmaf(x1.z, w2.w, a1[3]);
            a0[0] = fmaf(x0.w, w3.x, a0[0]); a0[1] = fmaf(x0.w, w3.y, a0[1]);
            a0[2] = fmaf(x0.w, w3.z, a0[2]); a0[3] = fmaf(x0.w, w3.w, a0[3]);
            a1[0] = fmaf(x1.w, w3.x, a1[0]); a1[1] = fmaf(x1.w, w3.y, a1[1]);
            a1[2] = fmaf(x1.w, w3.z, a1[2]); a1[3] = fmaf(x1.w, w3.w, a1[3]);
        }
        const float4 bs4 = *reinterpret_cast<const float4*>(bias + u0);
        const float4 lb4 = *reinterpret_cast<const float4*>(lb + u0);
        {
            float4 o;
            o.x = a0[0] + bs4.x; o.y = a0[1] + bs4.y;
            o.z = a0[2] + bs4.z; o.w = a0[3] + bs4.w;
            if (rt == 0) { o.x += lb4.x; o.y += lb4.y; o.z += lb4.z; o.w += lb4.w; }
            *reinterpret_cast<float4*>(&potl[0][rt * 2][u0]) = o;
        }
        {
            float4 o;
            o.x = a1[0] + bs4.x; o.y = a1[1] + bs4.y;
            o.z = a1[2] + bs4.z; o.w = a1[3] + bs4.w;
            *reinterpret_cast<float4*>(&potl[0][rt * 2 + 1][u0]) = o;
        }
    }

    // per-role persistent state
    float chain_r[16];
    const int prt = (tid & 255) >> 4;     // producer row-group (16 x 4 rows)
    const int pu0 = (tid & 15) * 4;       // producer col base
    float pacc[4][4];
    float4 xvA[4][4], xvB[4][4];          // x pipeline: [kq][row]

    // issue x loads for the slice belonging to step t_for (chunk (t>>6)+1)
    auto XLOAD = [&](float4 (&dst)[4][4], int t_for) {
        const int c = (t_for >> 6) + 1;
        const int s = t_for & 63;
        const float* xr = x + ((size_t)b * T_ + c * 64 + prt * 4) * F_ + s * 16;
#pragma unroll
        for (int kq = 0; kq < 4; ++kq)
#pragma unroll
            for (int i = 0; i < 4; ++i)
                dst[kq][i] = *reinterpret_cast<const float4*>(xr + (size_t)i * F_ + kq * 4);
    };
    auto WLOAD = [&](float4 (&wq)[4][4], int s) {
        const float* wr = w + (size_t)(s * 16) * U_ + pu0;
#pragma unroll
        for (int kq = 0; kq < 4; ++kq)
#pragma unroll
            for (int j = 0; j < 4; ++j)
                wq[kq][j] = *reinterpret_cast<const float4*>(wr + (size_t)(kq * 4 + j) * U_);
    };
    // 256 FMAs: per output (i,j), k ascending (kq outer, x-component inner)
    auto FMA16 = [&](const float4 (&cur)[4][4], const float4 (&wq)[4][4]) {
#pragma unroll
        for (int kq = 0; kq < 4; ++kq) {
            const float4 w0 = wq[kq][0], w1 = wq[kq][1];
            const float4 w2 = wq[kq][2], w3 = wq[kq][3];
#pragma unroll
            for (int i = 0; i < 4; ++i) {
                const float4 xc = cur[kq][i];
                pacc[i][0] = fmaf(xc.x, w0.x, pacc[i][0]);
                pacc[i][1] = fmaf(xc.x, w0.y, pacc[i][1]);
                pacc[i][2] = fmaf(xc.x, w0.z, pacc[i][2]);
                pacc[i][3] = fmaf(xc.x, w0.w, pacc[i][3]);
                pacc[i][0] = fmaf(xc.y, w1.x, pacc[i][0]);
                pacc[i][1] = fmaf(xc.y, w1.y, pacc[i][1]);
                pacc[i][2] = fmaf(xc.y, w1.z, pacc[i][2]);
                pacc[i][3] = fmaf(xc.y, w1.w, pacc[i][3]);
                pacc[i][0] = fmaf(xc.z, w2.x, pacc[i][0]);
                pacc[i][1] = fmaf(xc.z, w2.y, pacc[i][1]);
                pacc[i][2] = fmaf(xc.z, w2.z, pacc[i][2]);
                pacc[i][3] = fmaf(xc.z, w2.w, pacc[i][3]);
                pacc[i][0] = fmaf(xc.w, w3.x, pacc[i][0]);
                pacc[i][1] = fmaf(xc.w, w3.y, pacc[i][1]);
                pacc[i][2] = fmaf(xc.w, w3.z, pacc[i][2]);
                pacc[i][3] = fmaf(xc.w, w3.w, pacc[i][3]);
            }
        }
    };

    if (cons) {
#pragma unroll
        for (int k = 0; k < 16; ++k)
            chain_r[k] = chain[(size_t)(g * 16 + k) * U_ + u];
    } else {
        // slice 0 of chunk 1 ("step 0"): direct compute, then preload t=1
#pragma unroll
        for (int i = 0; i < 4; ++i)
#pragma unroll
            for (int j = 0; j < 4; ++j) pacc[i][j] = 0.f;
        float4 wq[4][4];
        WLOAD(wq, 0);
        XLOAD(xvB, 0);                    // xvB as scratch for slice 0
        FMA16(xvB, wq);
        XLOAD(xvA, 1);                    // pipeline prime for step t=1
    }
    __syncthreads();

    if (cons && g == 0) alpha_s[u] = potl[0][0][u];   // t=0 (bias+left)
    bar_lds();

    // one fused step: consumer = verbatim R6; producer = FMA(cur) + load(nxt)
    auto STEP = [&](int t, float4 (&cur)[4][4], float4 (&nxt)[4][4]) {
        const int c = (t >> 6) + 1;
        const int s = t & 63;
        if (cons) {
            const float pc = potl[(t >> 6) & 1][s][u];
            const float4* a4 = reinterpret_cast<const float4*>(alpha_s);
            float best = -3.402823466e38f;
            int bidx = 0;
#pragma unroll
            for (int q = 0; q < 4; ++q) {
                const float4 av = a4[g * 4 + q];
                const float avv[4] = {av.x, av.y, av.z, av.w};
#pragma unroll
                for (int kk = 0; kk < 4; ++kk) {
                    const int k = q * 4 + kk;
                    const float s2 = (avv[kk] + chain_r[k]) + pc;
                    if (s2 > best) { best = s2; bidx = g * 16 + k; }
                }
            }
            pval[g][u] = best;
            pidx[g][u] = bidx;
        } else {
            if (c < 8) {
                float4 wq[4][4];
                WLOAD(wq, s);             // w FIRST (older than x-next)
                const int tn = t + 1;
                if (tn < T_ && ((tn >> 6) + 1) < 8)
                    XLOAD(nxt, tn);       // x for t+1 stays in flight
                if (s == 0) {
#pragma unroll
                    for (int i = 0; i < 4; ++i)
#pragma unroll
                        for (int j = 0; j < 4; ++j) pacc[i][j] = 0.f;
                }
                FMA16(cur, wq);           // waits w (vmcnt 16), not x-next
            } else {
                const int tn = t + 1;
                if (tn < T_ && ((tn >> 6) + 1) < 8) XLOAD(nxt, tn);
            }
        }
        bar_lds();
        if (cons) {
            if (g == 0) {
                float bv = pval[0][u];
                int   bi = pidx[0][u];
#pragma unroll
                for (int j = 1; j < 4; ++j) {
                    const float v = pval[j][u];
                    if (v > bv) { bv = v; bi = pidx[j][u]; }  // lowest g on tie
                }
                bp[t - 1][u] = (unsigned char)bi;
                alpha_s[u] = bv;
            }
        } else if (c < 8 && s == 63) {
            const float4 bs4 = *reinterpret_cast<const float4*>(bias + pu0);
            const float4 rb4 = *reinterpret_cast<const float4*>(rb + pu0);
#pragma unroll
            for (int i = 0; i < 4; ++i) {
                const int row = c * 64 + prt * 4 + i;
                float4 o;
                o.x = pacc[i][0] + bs4.x; o.y = pacc[i][1] + bs4.y;
                o.z = pacc[i][2] + bs4.z; o.w = pacc[i][3] + bs4.w;
                if (row == T_ - 1) { o.x += rb4.x; o.y += rb4.y; o.z += rb4.z; o.w += rb4.w; }
                *reinterpret_cast<float4*>(&potl[c & 1][row & 63][pu0]) = o;
            }
        }
        bar_lds();
    };

    // 2-unrolled ping-pong (static reg-set selection, rule #20 safe)
    for (int t = 1; t + 1 < T_; t += 2) {
        STEP(t, xvA, xvB);
        STEP(t + 1, xvB, xvA);
    }
    STEP(T_ - 1, xvA, xvB);               // t = 511 (producer idle)

    __syncthreads();

    // ---------------- backtrace (validated 2-pass segmented) ----------------
    if (cons) {
        const int r0c = g * 128;
        const int r1c = (g == 3) ? (T_ - 1) : (g + 1) * 128;
        int tag = lane;
        for (int r = r1c - 1; r >= r0c; --r) tag = bp[r][tag];
        cmap[g][lane] = (unsigned char)tag;
    }
    __syncthreads();

    if (tid == 0) {
        float bvv = alpha_s[0];
        int bii = 0;
        for (int v = 1; v < 64; ++v) {
            const float a = alpha_s[v];
            if (a > bvv) { bvv = a; bii = v; }   // strict >: first occurrence
        }
        path[(size_t)b * T_ + (T_ - 1)] = bii;
        const int e3 = bii;                 // tag_511
        const int e2 = cmap[3][e3];         // tag_384
        const int e1 = cmap[2][e2];         // tag_256
        const int e0 = cmap[1][e1];         // tag_128
        es[0] = e0; es[1] = e1; es[2] = e2; es[3] = e3;
    }
    __syncthreads();

    if (cons && lane == 0) {
        const int r0c = g * 128;
        const int r1c = (g == 3) ? (T_ - 1) : (g + 1) * 128;
        int tag = es[g];
        int* pb = path + (size_t)b * T_;
        for (int r = r1c - 1; r >= r0c; --r) {
            tag = bp[r][tag];
            pb[r] = tag;
        }
    }
}

extern "C" void kernel_launch(void* const* d_in, const int* in_sizes, int n_in,
                              void* d_out, int out_size, void* d_ws, size_t ws_size,
                              hipStream_t stream) {
    const float* x  = (const float*)d_in[0];
    const float* w  = (const float*)d_in[1];
    const float* bs = (const float*)d_in[2];
    const float* ck = (const float*)d_in[3];
    const float* lb = (const float*)d_in[4];
    const float* rb = (const float*)d_in[5];
    int* path = (int*)d_out;            // [B][T] int32

    crf_fused_kernel<<<dim3(B_), dim3(512), 0, stream>>>(x, w, bs, ck, lb, rb, path);
}

// Round 24
// 344.545 us; speedup vs baseline: 2.3612x; 2.3612x over previous
//
#include <hip/hip_runtime.h>

#define B_ 64
#define T_ 512
#define F_ 1024
#define U_ 64
#define FK 128            // k-chunk staged in LDS (GEMM)
#define NCH (F_ / FK)     // 8 chunks

// ---------------------------------------------------------------------------
// Kernel 1: potentials = x @ w + bias (+ boundaries).  32768 x 64.
// VERBATIM round-5 kernel -- best measured GEMM (~109us, validated 7x):
// 64-row block, 4 rows x 4 cols per thread, grid 512 (2 blocks/CU).
// w staged K-chunk-wise into LDS (32 KB), next chunk's loads issued before
// the compute phase. Rolling (non-unrolled) kk loop. Per-output
// accumulation: ascending f, sequential fmaf. DO NOT TOUCH.
// ---------------------------------------------------------------------------
__global__ __launch_bounds__(256, 2) void crf_gemm_kernel(
    const float* __restrict__ x, const float* __restrict__ w,
    const float* __restrict__ bias, const float* __restrict__ lb,
    const float* __restrict__ rb, float* __restrict__ pot)
{
    __shared__ float wlds[FK * U_];     // 32 KB, [k][u] row-major

    const int tid = threadIdx.x;
    const int rt = tid >> 4;            // 16 row-groups x 4 rows
    const int ut = tid & 15;            // 16 col-groups x 4 cols
    const int n0 = blockIdx.x * 64;
    const int r0 = rt * 4;
    const int u0 = ut * 4;

    float acc[4][4];
#pragma unroll
    for (int i = 0; i < 4; ++i)
#pragma unroll
        for (int j = 0; j < 4; ++j) acc[i][j] = 0.f;

    const float* xrow = x + (size_t)(n0 + r0) * F_;

    // ---- stage chunk 0 ----
    float4 wst[8];
#pragma unroll
    for (int l = 0; l < 8; ++l)
        wst[l] = *reinterpret_cast<const float4*>(w + (size_t)(l * 256 + tid) * 4);
#pragma unroll
    for (int l = 0; l < 8; ++l)
        *reinterpret_cast<float4*>(&wlds[(l * 256 + tid) * 4]) = wst[l];
    __syncthreads();

    // ---- x distance-2 register pipeline (global-k indexed) ----
    float4 xp0[4], xp1[4];
#pragma unroll
    for (int i = 0; i < 4; ++i)
        xp0[i] = *reinterpret_cast<const float4*>(xrow + (size_t)i * F_ + 0);
#pragma unroll
    for (int i = 0; i < 4; ++i)
        xp1[i] = *reinterpret_cast<const float4*>(xrow + (size_t)i * F_ + 4);

    for (int c = 0; c < NCH; ++c) {
        // issue next chunk's stage loads early (land during compute)
        if (c + 1 < NCH) {
#pragma unroll
            for (int l = 0; l < 8; ++l)
                wst[l] = *reinterpret_cast<const float4*>(
                    w + (size_t)(c + 1) * (FK * U_) + (size_t)(l * 256 + tid) * 4);
        }

        // w LDS read, prefetched one iter ahead
        float4 wc[4];
#pragma unroll
        for (int j = 0; j < 4; ++j)
            wc[j] = *reinterpret_cast<const float4*>(&wlds[(0 + j) * U_ + u0]);

        for (int kk = 0; kk < FK / 4; ++kk) {
            // prefetch x at global k = c*128 + kk*4 + 8 (wrap: harmless)
            const int kg = (c * FK + kk * 4 + 8) & (F_ - 1);
            float4 xn[4];
#pragma unroll
            for (int i = 0; i < 4; ++i)
                xn[i] = *reinterpret_cast<const float4*>(xrow + (size_t)i * F_ + kg);

            // prefetch next iter's w rows ((kk+1)*4, wraps to 0 at chunk end)
            float4 wn[4];
            const int krn = (kk * 4 + 4) & (FK - 1);
#pragma unroll
            for (int j = 0; j < 4; ++j)
                wn[j] = *reinterpret_cast<const float4*>(&wlds[(krn + j) * U_ + u0]);

            // 64 FMAs, f ascending per output
#pragma unroll
            for (int ff = 0; ff < 4; ++ff) {
                const float4 wf = wc[ff];
#pragma unroll
                for (int i = 0; i < 4; ++i) {
                    const float xs = (ff == 0) ? xp0[i].x : (ff == 1) ? xp0[i].y
                                   : (ff == 2) ? xp0[i].z : xp0[i].w;
                    acc[i][0] = fmaf(xs, wf.x, acc[i][0]);
                    acc[i][1] = fmaf(xs, wf.y, acc[i][1]);
                    acc[i][2] = fmaf(xs, wf.z, acc[i][2]);
                    acc[i][3] = fmaf(xs, wf.w, acc[i][3]);
                }
            }
#pragma unroll
            for (int i = 0; i < 4; ++i) { xp0[i] = xp1[i]; xp1[i] = xn[i]; }
#pragma unroll
            for (int j = 0; j < 4; ++j) wc[j] = wn[j];
        }

        if (c + 1 < NCH) {
            __syncthreads();            // all reads of current chunk done
#pragma unroll
            for (int l = 0; l < 8; ++l)
                *reinterpret_cast<float4*>(&wlds[(l * 256 + tid) * 4]) = wst[l];
            __syncthreads();
        }
    }

    // ---- epilogue ----
    const int t0 = n0 & (T_ - 1);       // 64 | 512: one batch per block
    const float4 bs4 = *reinterpret_cast<const float4*>(bias + u0);
    const float4 lb4 = *reinterpret_cast<const float4*>(lb + u0);
    const float4 rb4 = *reinterpret_cast<const float4*>(rb + u0);

#pragma unroll
    for (int i = 0; i < 4; ++i) {
        const int n = n0 + r0 + i;
        const int t = t0 + r0 + i;
        float4 o;
        o.x = acc[i][0] + bs4.x;
        o.y = acc[i][1] + bs4.y;
        o.z = acc[i][2] + bs4.z;
        o.w = acc[i][3] + bs4.w;
        if (t == 0)      { o.x += lb4.x; o.y += lb4.y; o.z += lb4.z; o.w += lb4.w; }
        if (t == T_ - 1) { o.x += rb4.x; o.y += rb4.y; o.z += rb4.z; o.w += rb4.w; }
        *reinterpret_cast<float4*>(pot + (size_t)n * U_ + u0) = o;
    }
}

// ---------------------------------------------------------------------------
// Kernel 2: Viterbi, one block (4 waves) per batch. VERBATIM R6 kernel --
// best DIRECTLY-MEASURED viterbi (235us, absmax=0, confirmed R21): thread
// (g,u) covers v in [g*16, g*16+16); serial 16-candidate compare chain;
// plain __syncthreads x2 per step; distance-1 pot prefetch; g0 combines
// (ascending g, strict >) and writes alpha + bp. 13 restructures (DPP,
// tournament, lgkm-barriers, swizzles, co-residency, fusion x2) all
// measured slower. Exact arithmetic: s = (alpha[v] + chain[v][u]) +
// pot[t][u], strict >, ascending v == jnp.argmax first occurrence.
// Segmented 2-pass backtrace (validated, integer-exact).
// ---------------------------------------------------------------------------
__global__ __launch_bounds__(256) void crf_viterbi_kernel(
    const float* __restrict__ pot, const float* __restrict__ chain,
    int* __restrict__ path)
{
    const int b = blockIdx.x;
    const int tid = threadIdx.x;
    const int u = tid & 63;
    const int g = tid >> 6;   // wave 0..3

    __shared__ __align__(16) float alpha_s[64];
    __shared__ float pval[4][64];
    __shared__ int   pidx[4][64];
    __shared__ unsigned char bp[T_ - 1][64];   // 32704 B
    __shared__ unsigned char cmap[4][64];
    __shared__ int es[4];

    float chain_r[16];
#pragma unroll
    for (int k = 0; k < 16; ++k)
        chain_r[k] = chain[(size_t)(g * 16 + k) * U_ + u];

    const float* potb = pot + (size_t)b * T_ * U_;

    if (g == 0) alpha_s[u] = potb[u];          // t = 0 (bias + left included)
    __syncthreads();

    float pc = potb[(size_t)U_ + u];           // pot[1][u]

    for (int t = 1; t < T_; ++t) {
        // prefetch next pot row (hides latency under the inner loop)
        const int tn = (t + 1 < T_) ? (t + 1) : (T_ - 1);
        const float pn = potb[(size_t)tn * U_ + u];

        const float4* a4 = reinterpret_cast<const float4*>(alpha_s);
        float best = -3.402823466e38f;
        int bidx = 0;
#pragma unroll
        for (int q = 0; q < 4; ++q) {
            const float4 av = a4[g * 4 + q];
            const float avv[4] = {av.x, av.y, av.z, av.w};
#pragma unroll
            for (int kk = 0; kk < 4; ++kk) {
                const int k = q * 4 + kk;
                const float s2 = (avv[kk] + chain_r[k]) + pc;
                if (s2 > best) { best = s2; bidx = g * 16 + k; }
            }
        }
        pval[g][u] = best;
        pidx[g][u] = bidx;
        __syncthreads();
        if (g == 0) {
            float bv = pval[0][u];
            int   bi = pidx[0][u];
#pragma unroll
            for (int j = 1; j < 4; ++j) {
                const float v = pval[j][u];
                if (v > bv) { bv = v; bi = pidx[j][u]; }   // strict >: lowest g wins ties
            }
            bp[t - 1][u] = (unsigned char)bi;
            alpha_s[u] = bv;
        }
        __syncthreads();
        pc = pn;
    }

    // ---- backtrace (2-pass segmented, integer-exact, validated) ----
    const int r0c = g * 128;
    const int r1c = (g == 3) ? (T_ - 1) : (g + 1) * 128;

    {   // pass 1: composed map of my segment from every possible start tag
        int tag = u;
        for (int r = r1c - 1; r >= r0c; --r) tag = bp[r][tag];
        cmap[g][u] = (unsigned char)tag;
    }
    __syncthreads();

    if (tid == 0) {
        // final argmax over alpha (first occurrence)
        float bvv = alpha_s[0];
        int bii = 0;
        for (int v = 1; v < 64; ++v) {
            const float a = alpha_s[v];
            if (a > bvv) { bvv = a; bii = v; }
        }
        path[(size_t)b * T_ + (T_ - 1)] = bii;
        const int e3 = bii;                 // tag_511
        const int e2 = cmap[3][e3];         // tag_384
        const int e1 = cmap[2][e2];         // tag_256
        const int e0 = cmap[1][e1];         // tag_128
        es[0] = e0; es[1] = e1; es[2] = e2; es[3] = e3;
    }
    __syncthreads();

    // pass 2: 4 parallel chases over disjoint row ranges (exact replica of
    // the sequential loop: tag_r = bp[r][tag_{r+1}], path[r] = tag_r)
    if (u == 0) {
        int tag = es[g];                    // tag at row r1c (g==3: tag_511)
        int* pb = path + (size_t)b * T_;
        for (int r = r1c - 1; r >= r0c; --r) {
            tag = bp[r][tag];
            pb[r] = tag;
        }
    }
}

extern "C" void kernel_launch(void* const* d_in, const int* in_sizes, int n_in,
                              void* d_out, int out_size, void* d_ws, size_t ws_size,
                              hipStream_t stream) {
    const float* x  = (const float*)d_in[0];
    const float* w  = (const float*)d_in[1];
    const float* bs = (const float*)d_in[2];
    const float* ck = (const float*)d_in[3];
    const float* lb = (const float*)d_in[4];
    const float* rb = (const float*)d_in[5];

    float* pot = (float*)d_ws;          // [B*T][U] f32 = 8.39 MB
    int* path  = (int*)d_out;           // [B][T] int32

    crf_gemm_kernel<<<dim3(B_ * T_ / 64), dim3(256), 0, stream>>>(x, w, bs, lb, rb, pot);
    crf_viterbi_kernel<<<dim3(B_), dim3(256), 0, stream>>>(pot, ck, path);
}